// Round 13
// baseline (229.268 us; speedup 1.0000x reference)
//
#include <hip/hip_runtime.h>
#include <stdint.h>

typedef unsigned short u16;

#define Bb 4
#define Hh 4
#define Tt 8
#define Cc 256
#define NP 196
#define Ss 1568                 // Tt*NP
#define SCALE_S 0.0252538136f   // 1/sqrt(1568)
#define LST 32                  // LDS row stride for gemm_bt_core tiles
#define KC 64                   // k_fused KV chunk
#define NCH 25                  // ceil(1568/64)
#define LPP 72                  // P tile row stride (64+8)

typedef __attribute__((ext_vector_type(4))) float floatx4;
typedef __attribute__((ext_vector_type(8))) short shortx8;

__device__ __forceinline__ float bf2f(u16 u) {
    union { unsigned u; float f; } v; v.u = ((unsigned)u) << 16; return v.f;
}
__device__ __forceinline__ u16 f2bf(float f) {
    union { float f; unsigned u; } v; v.f = f;
    unsigned r = v.u + 0x7FFFu + ((v.u >> 16) & 1u);
    return (u16)(r >> 16);
}

typedef const __attribute__((address_space(1))) void* gas1_t;
typedef __attribute__((address_space(3))) void* las3_t;
__device__ __forceinline__ void gld16(const void* g, void* l) {
    __builtin_amdgcn_global_load_lds((gas1_t)g, (las3_t)l, 16, 0, 0);
}

// ---- K0: all weights fp32 -> one bf16 buffer [Wq|Wk|Wv|Wo] ----
__global__ __launch_bounds__(256) void k_convall(const float* __restrict__ Wq,
                                                 const float* __restrict__ Wk,
                                                 const float* __restrict__ Wv,
                                                 const float* __restrict__ Wo,
                                                 u16* __restrict__ dst) {
    const int NW = Hh * Cc * Cc;     // 262144
    int i = blockIdx.x * 256 + threadIdx.x;
    float v;
    if (i < NW) v = Wq[i];
    else if (i < 2 * NW) v = Wk[i - NW];
    else if (i < 3 * NW) v = Wv[i - 2 * NW];
    else if (i < 3 * NW + Cc * Cc) v = Wo[i - 3 * NW];
    else return;
    dst[i] = f2bf(v);
}

// One BK=32 step: 4x4 grid of 16x16x32 bf16 MFMAs per wave (wave covers 64x64).
__device__ __forceinline__ void mfma_step(const u16* As, const u16* Bs, int lane,
                                          int wm, int wn, floatx4 acc[4][4]) {
    const int r15 = lane & 15;
    const int kq  = (lane >> 4) << 3;
    shortx8 a[4], b[4];
#pragma unroll
    for (int i = 0; i < 4; ++i)
        a[i] = *(const shortx8*)(As + (wm * 64 + i * 16 + r15) * LST + kq);
#pragma unroll
    for (int j = 0; j < 4; ++j)
        b[j] = *(const shortx8*)(Bs + (wn * 64 + j * 16 + r15) * LST + kq);
#pragma unroll
    for (int i = 0; i < 4; ++i)
#pragma unroll
        for (int j = 0; j < 4; ++j)
            acc[i][j] = __builtin_amdgcn_mfma_f32_16x16x32_bf16(a[i], b[j], acc[i][j], 0, 0, 0);
}

// C[m,n] = sum_k A[m,k]*B[n,k], 128x128 tile, depth-2 prefetch.
__device__ __forceinline__ void gemm_bt_core(const u16* A, const u16* Bm, int lda, int ldb,
                                             int mbase, int mlast, int nbase, int nlast,
                                             int KD, u16* As, u16* Bs, floatx4 acc[4][4]) {
    int tid = threadIdx.x;
    int lane = tid & 63, wave = tid >> 6, wm = wave >> 1, wn = wave & 1;
    int row0 = tid >> 2, row1 = 64 + row0;
    int cole = (tid & 3) << 3;                 // 0,8,16,24
    int ga0 = mbase + row0; ga0 = ga0 <= mlast ? ga0 : mlast;
    int ga1 = mbase + row1; ga1 = ga1 <= mlast ? ga1 : mlast;
    int gb0 = nbase + row0; gb0 = gb0 <= nlast ? gb0 : nlast;
    int gb1 = nbase + row1; gb1 = gb1 <= nlast ? gb1 : nlast;
    const u16* pa0 = A  + (size_t)ga0 * lda + cole;
    const u16* pa1 = A  + (size_t)ga1 * lda + cole;
    const u16* pb0 = Bm + (size_t)gb0 * ldb + cole;
    const u16* pb1 = Bm + (size_t)gb1 * ldb + cole;
    shortx8 xa0 = *(const shortx8*)(pa0),      xa1 = *(const shortx8*)(pa1);
    shortx8 xb0 = *(const shortx8*)(pb0),      xb1 = *(const shortx8*)(pb1);
    shortx8 ya0 = *(const shortx8*)(pa0 + 32), ya1 = *(const shortx8*)(pa1 + 32);
    shortx8 yb0 = *(const shortx8*)(pb0 + 32), yb1 = *(const shortx8*)(pb1 + 32);
    for (int k0 = 0; k0 < KD; k0 += 64) {
        __syncthreads();
        *(shortx8*)(As + row0 * LST + cole) = xa0;
        *(shortx8*)(As + row1 * LST + cole) = xa1;
        *(shortx8*)(Bs + row0 * LST + cole) = xb0;
        *(shortx8*)(Bs + row1 * LST + cole) = xb1;
        int kp = k0 + 64;
        if (kp < KD) {
            xa0 = *(const shortx8*)(pa0 + kp); xa1 = *(const shortx8*)(pa1 + kp);
            xb0 = *(const shortx8*)(pb0 + kp); xb1 = *(const shortx8*)(pb1 + kp);
        }
        __syncthreads();
        mfma_step(As, Bs, lane, wm, wn, acc);
        if (k0 + 32 < KD) {
            __syncthreads();
            *(shortx8*)(As + row0 * LST + cole) = ya0;
            *(shortx8*)(As + row1 * LST + cole) = ya1;
            *(shortx8*)(Bs + row0 * LST + cole) = yb0;
            *(shortx8*)(Bs + row1 * LST + cole) = yb1;
            int kq2 = k0 + 96;
            if (kq2 < KD) {
                ya0 = *(const shortx8*)(pa0 + kq2); ya1 = *(const shortx8*)(pa1 + kq2);
                yb0 = *(const shortx8*)(pb0 + kq2); yb1 = *(const shortx8*)(pb1 + kq2);
            }
            __syncthreads();
            mfma_step(As, Bs, lane, wm, wn, acc);
        }
    }
}

// ---- K1: emb fp32 [B,T,C,N] -> x bf16 [B,S,C] ----
__global__ void k_transpose(const float* __restrict__ emb, u16* __restrict__ x) {
    __shared__ u16 tile[32][33];
    int bt = blockIdx.z;
    int c0 = blockIdx.y * 32, n0 = blockIdx.x * 32;
    const float* src = emb + (size_t)bt * Cc * NP;
#pragma unroll
    for (int rr = 0; rr < 32; rr += 8) {
        int c = c0 + threadIdx.y + rr;
        int n = n0 + threadIdx.x;
        u16 v = 0;
        if (n < NP) v = f2bf(src[(size_t)c * NP + n]);
        tile[threadIdx.y + rr][threadIdx.x] = v;
    }
    __syncthreads();
    int b = bt / Tt, t = bt % Tt;
    u16* dst = x + ((size_t)b * Ss + (size_t)t * NP) * Cc;
#pragma unroll
    for (int rr = 0; rr < 32; rr += 8) {
        int n = n0 + threadIdx.y + rr;
        int c = c0 + threadIdx.x;
        if (n < NP) dst[(size_t)n * Cc + c] = tile[threadIdx.x][threadIdx.y + rr];
    }
}

// ---- K2: QKV projections. V written transposed [C,S]. (round-0 form) ----
__global__ __launch_bounds__(256) void k_qkv(const u16* __restrict__ x,
                                             const u16* __restrict__ Wall,
                                             u16* __restrict__ Q, u16* __restrict__ Kb,
                                             u16* __restrict__ Vt) {
    __shared__ __align__(16) u16 As[128 * LST], Bs[128 * LST];
    floatx4 acc[4][4];
#pragma unroll
    for (int i = 0; i < 4; ++i)
#pragma unroll
        for (int j = 0; j < 4; ++j) acc[i][j] = (floatx4)(0.f);
    int z = blockIdx.z;
    int qkv = z >> 4, bh = z & 15, b = bh >> 2, h = bh & 3;
    const u16* A = x + (size_t)b * Ss * Cc;
    const u16* W = Wall + (size_t)qkv * Hh * Cc * Cc + (size_t)h * Cc * Cc;
    int mbase = blockIdx.y * 128, nbase = blockIdx.x * 128;
    gemm_bt_core(A, W, Cc, Cc, mbase, Ss - 1, nbase, Cc - 1, Cc, As, Bs, acc);

    int tid = threadIdx.x, lane = tid & 63, wave = tid >> 6, wm = wave >> 1, wn = wave & 1;
    int rq = (lane >> 4) << 2, cn = lane & 15;
    if (qkv < 2) {
        u16* out = (qkv == 0 ? Q : Kb) + (size_t)bh * Ss * Cc;
#pragma unroll
        for (int i = 0; i < 4; ++i) {
            int mb = mbase + wm * 64 + i * 16 + rq;
#pragma unroll
            for (int j = 0; j < 4; ++j) {
                int n = nbase + wn * 64 + j * 16 + cn;
#pragma unroll
                for (int r = 0; r < 4; ++r) {
                    int m = mb + r;
                    if (m < Ss) out[(size_t)m * Cc + n] = f2bf(acc[i][j][r]);
                }
            }
        }
    } else {
        u16* out = Vt + (size_t)bh * Cc * Ss;
#pragma unroll
        for (int i = 0; i < 4; ++i) {
            int m0 = mbase + wm * 64 + i * 16 + rq;
            if (m0 < Ss) {
#pragma unroll
                for (int j = 0; j < 4; ++j) {
                    int n = nbase + wn * 64 + j * 16 + cn;
                    ushort4 v;
                    v.x = f2bf(acc[i][j][0]); v.y = f2bf(acc[i][j][1]);
                    v.z = f2bf(acc[i][j][2]); v.w = f2bf(acc[i][j][3]);
                    *(ushort4*)(out + (size_t)n * Ss + m0) = v;
                }
            }
        }
    }
}

// ---- K3: stats only (round-2 form). sum/sumsq of (Q K^T)*SCALE_S per (b,h).
// 2704 blocks, XCD remap for L2 locality, no Sc write. ----
__global__ __launch_bounds__(256) void k_stats(const u16* __restrict__ Q,
                                               const u16* __restrict__ Kb,
                                               float* __restrict__ stats) {
    __shared__ __align__(16) u16 As[128 * LST], Bs[128 * LST];
    __shared__ float sred[8];
    floatx4 acc[4][4];
#pragma unroll
    for (int i = 0; i < 4; ++i)
#pragma unroll
        for (int j = 0; j < 4; ++j) acc[i][j] = (floatx4)(0.f);
    int L = blockIdx.x;                       // 2704 = 8 xcd * 2 bh * 169 tiles
    int xcd = L & 7, idx = L >> 3;
    int bh = xcd + 8 * (idx / 169);
    int rem = idx % 169;
    int mbase = (rem / 13) * 128, nbase = (rem % 13) * 128;
    const u16* A  = Q  + (size_t)bh * Ss * Cc;
    const u16* Bm = Kb + (size_t)bh * Ss * Cc;
    gemm_bt_core(A, Bm, Cc, Cc, mbase, Ss - 1, nbase, Ss - 1, Cc, As, Bs, acc);

    int tid = threadIdx.x, lane = tid & 63, wave = tid >> 6, wm = wave >> 1, wn = wave & 1;
    int rq = (lane >> 4) << 2, cn = lane & 15;
    float lsum = 0.f, lsq = 0.f;
#pragma unroll
    for (int i = 0; i < 4; ++i) {
        int mb = mbase + wm * 64 + i * 16 + rq;
#pragma unroll
        for (int j = 0; j < 4; ++j) {
            int n = nbase + wn * 64 + j * 16 + cn;
            bool nv = n < Ss;
#pragma unroll
            for (int r = 0; r < 4; ++r) {
                int m = mb + r;
                if (nv && m < Ss) {
                    float v = acc[i][j][r] * SCALE_S;
                    lsum += v; lsq += v * v;
                }
            }
        }
    }
#pragma unroll
    for (int mk = 1; mk <= 32; mk <<= 1) { lsum += __shfl_xor(lsum, mk); lsq += __shfl_xor(lsq, mk); }
    if (lane == 0) { sred[wave] = lsum; sred[4 + wave] = lsq; }
    __syncthreads();
    if (tid == 0) atomicAdd(&stats[bh * 4 + 0], sred[0] + sred[1] + sred[2] + sred[3]);
    if (tid == 1) atomicAdd(&stats[bh * 4 + 1], sred[4] + sred[5] + sred[6] + sred[7]);
}

// ---- K4: fused QK^T + norm + exp + PV + head-mean. M=64, 4 waves, KC=64,
// 400 blocks, LDS 75.5 KB. Single change vs r12: barrier 1 of the chunk loop
// is LDS-only (lgkmcnt(0)+s_barrier, m201 pattern) so the next-chunk K-DMA and
// V loads stay in flight until barrier 2's full drain — removing the forced
// early vmcnt(0) stall each chunk. Barrier 2 remains __syncthreads. ----
__global__ __launch_bounds__(256, 2) void k_fused(const u16* __restrict__ Q,
                                                  const u16* __restrict__ Kb,
                                                  const u16* __restrict__ Vt,
                                                  const float* __restrict__ stats,
                                                  float* __restrict__ ctxm) {
    extern __shared__ u16 smem[];
    u16* Kls = smem;                             // 2 x [64][256] linear+swz = 65536 B
    u16* Ps  = smem + 32768;                     // [64][LPP] = 9216 B
    float* rsp = (float*)((char*)smem + 74752);  // [2][64]
    float* rs2 = rsp + 128;                      // [64]

    int L = blockIdx.x;                      // 400 = 8 xcd * 2 bh * 25 m-tiles
    int xcd = L & 7, idx = L >> 3;
    int bh = xcd + 8 * (idx / 25);
    int mt = idx % 25;
    int mbase = mt * 64;

    float inv  = 1.f / ((float)Ss * (float)Ss);
    float mean = stats[bh * 4] * inv;
    float var  = fmaxf(stats[bh * 4 + 1] * inv - mean * mean, 0.f);
    float istd = rsqrtf(var + 1e-5f);
    float aa   = istd * 1.44269504f;
    float aas  = aa * SCALE_S;
    float bb   = -mean * aa;

    const u16* Qp = Q  + (size_t)bh * Ss * Cc;
    const u16* Kp = Kb + (size_t)bh * Ss * Cc;
    const u16* Vp = Vt + (size_t)bh * Cc * Ss;

    int tid = threadIdx.x, lane = tid & 63, wv = tid >> 6;
    const int r15 = lane & 15;
    const int g   = lane >> 4;
    const int kq  = g << 3;                  // elem offset of k-slice
    const int prow = g << 2;
    const int wqm = wv >> 1, wqn = wv & 1;   // QK^T wave grid: 2m x 2n
    const int swz = (r15 & 7) << 4;          // read-side XOR (Kls)

    // ---- Q fragments -> registers (once). QK^T wave owns rows [wqm*32, +32). ----
    shortx8 Qa[8][2];
#pragma unroll
    for (int kk = 0; kk < 8; ++kk)
#pragma unroll
        for (int i = 0; i < 2; ++i) {
            int row = mbase + wqm * 32 + i * 16 + r15;
            row = row < Ss ? row : Ss - 1;
            Qa[kk][i] = *(const shortx8*)(Qp + (size_t)row * Cc + kk * 32 + kq);
        }

    // ---- prologue: DMA K chunk 0 (pre-swizzled source, linear dest) ----
#pragma unroll
    for (int pass = 0; pass < 8; ++pass) {
        int rb = pass * 4 + wv;              // 2-row unit (0..31)
        int r2 = rb * 2 + (lane >> 5);
        int colb = (lane & 31) << 4;
        int scol = colb ^ ((r2 & 7) << 4);
        gld16((const char*)Kp + (size_t)r2 * 512 + scol, Kls + rb * 512);
    }
    __syncthreads();

    floatx4 acc[4][4];
#pragma unroll
    for (int i = 0; i < 4; ++i)
#pragma unroll
        for (int j = 0; j < 4; ++j) acc[i][j] = (floatx4)(0.f);
    float rsum[2][4];
    rsum[0][0] = rsum[0][1] = rsum[0][2] = rsum[0][3] = 0.f;
    rsum[1][0] = rsum[1][1] = rsum[1][2] = rsum[1][3] = 0.f;

    int cur = 0;
    for (int c = 0; c < NCH; ++c) {
        int kc = c * KC;
        const u16* Kcur = Kls + cur * 16384;
        // issue DMA of next K chunk (in flight through barrier 1; drained at barrier 2,
        // one full chunk before its consumer QK^T(c+1))
        if (c + 1 < NCH) {
            int kc1 = kc + KC;
            u16* Knxt = Kls + (cur ^ 1) * 16384;
#pragma unroll
            for (int pass = 0; pass < 8; ++pass) {
                int rb = pass * 4 + wv;
                int r2 = rb * 2 + (lane >> 5);
                int colb = (lane & 31) << 4;
                int scol = colb ^ ((r2 & 7) << 4);
                int grow = kc1 + r2; grow = grow < Ss ? grow : 0;
                gld16((const char*)Kp + (size_t)grow * 512 + scol, Knxt + rb * 512);
            }
        }
        // prefetch V frags (PV wave owns ctx cols [wv*64,+64)); 8 loads
        shortx8 vf[2][4];
#pragma unroll
        for (int kk2 = 0; kk2 < 2; ++kk2)
#pragma unroll
            for (int nj = 0; nj < 4; ++nj) {
                int vr = wv * 64 + nj * 16 + r15;
                int vc = kc + kk2 * 32 + kq;
                vc = (vc + 8 <= Ss) ? vc : 0;
                vf[kk2][nj] = *(const shortx8*)(Vp + (size_t)vr * Ss + vc);
            }
        // ---- QK^T: wave tile 32 rows x 32 kv cols ----
        floatx4 accs[2][2];
        accs[0][0] = (floatx4)(0.f); accs[0][1] = (floatx4)(0.f);
        accs[1][0] = (floatx4)(0.f); accs[1][1] = (floatx4)(0.f);
        const int cb = g << 4;
#pragma unroll
        for (int kk = 0; kk < 8; ++kk) {
            int cbx = (kk * 64 + cb) ^ swz;
            shortx8 b0 = *(const shortx8*)((const char*)Kcur + (wqn * 32 + r15) * 512 + cbx);
            shortx8 b1 = *(const shortx8*)((const char*)Kcur + (wqn * 32 + 16 + r15) * 512 + cbx);
            accs[0][0] = __builtin_amdgcn_mfma_f32_16x16x32_bf16(Qa[kk][0], b0, accs[0][0], 0, 0, 0);
            accs[1][0] = __builtin_amdgcn_mfma_f32_16x16x32_bf16(Qa[kk][1], b0, accs[1][0], 0, 0, 0);
            accs[0][1] = __builtin_amdgcn_mfma_f32_16x16x32_bf16(Qa[kk][0], b1, accs[0][1], 0, 0, 0);
            accs[1][1] = __builtin_amdgcn_mfma_f32_16x16x32_bf16(Qa[kk][1], b1, accs[1][1], 0, 0, 0);
        }
        // ---- exp on fp32 acc; mask invalid kv cols; accumulate row sums ----
#pragma unroll
        for (int j = 0; j < 2; ++j) {
            bool valid = (kc + wqn * 32 + j * 16 + r15) < Ss;
#pragma unroll
            for (int i = 0; i < 2; ++i)
#pragma unroll
                for (int r = 0; r < 4; ++r) {
                    float ex = valid ? exp2f(accs[i][j][r] * aas + bb) : 0.f;
                    accs[i][j][r] = ex;
                    rsum[i][r] += ex;
                }
        }
        // ---- barrier 1: LDS-only (prev PV's ds_reads of Ps done). DMA/V fly on. ----
        asm volatile("s_waitcnt lgkmcnt(0)" ::: "memory");
        __builtin_amdgcn_sched_barrier(0);
        __builtin_amdgcn_s_barrier();
        // ---- write P (D-layout -> row-major [m][kv]) ----
#pragma unroll
        for (int i = 0; i < 2; ++i)
#pragma unroll
            for (int j = 0; j < 2; ++j)
#pragma unroll
                for (int r = 0; r < 4; ++r)
                    Ps[(wqm * 32 + i * 16 + prow + r) * LPP + wqn * 32 + j * 16 + r15] =
                        f2bf(accs[i][j][r]);
        __syncthreads();   // barrier 2: full drain (P visible; K-DMA landed; V loaded)
        // ---- PV: wave owns all 64 rows x ctx cols [wv*64,+64) ----
#pragma unroll
        for (int kk2 = 0; kk2 < 2; ++kk2) {
            shortx8 pa_[4];
#pragma unroll
            for (int i2 = 0; i2 < 4; ++i2)
                pa_[i2] = *(const shortx8*)(Ps + (i2 * 16 + r15) * LPP + kk2 * 32 + kq);
#pragma unroll
            for (int i2 = 0; i2 < 4; ++i2)
#pragma unroll
                for (int nj = 0; nj < 4; ++nj)
                    acc[i2][nj] = __builtin_amdgcn_mfma_f32_16x16x32_bf16(
                        pa_[i2], vf[kk2][nj], acc[i2][nj], 0, 0, 0);
        }
        cur ^= 1;
    }

    // ---- row-sum: reduce over 16 col-lanes, combine the two wqn halves ----
#pragma unroll
    for (int i = 0; i < 2; ++i)
#pragma unroll
        for (int r = 0; r < 4; ++r) {
            float v = rsum[i][r];
            v += __shfl_xor(v, 1); v += __shfl_xor(v, 2);
            v += __shfl_xor(v, 4); v += __shfl_xor(v, 8);
            if (r15 == 0) rsp[wqn * 64 + wqm * 32 + i * 16 + prow + r] = v;
        }
    __syncthreads();
    if (tid < 64) rs2[tid] = rsp[tid] + rsp[64 + tid];
    __syncthreads();

    // ---- fused head-mean: ctxm[b,m,n] += 0.25 * acc / rowsum[m] ----
    int b = bh >> 2;
    float* outp = ctxm + (size_t)b * Ss * Cc;
#pragma unroll
    for (int i2 = 0; i2 < 4; ++i2) {
#pragma unroll
        for (int r = 0; r < 4; ++r) {
            int ml = i2 * 16 + prow + r;
            int m = mbase + ml;
            if (m < Ss) {
                float invs = 0.25f / rs2[ml];
#pragma unroll
                for (int nj = 0; nj < 4; ++nj) {
                    int n = wv * 64 + nj * 16 + r15;
                    atomicAdd(&outp[(size_t)m * Cc + n], acc[i2][nj][r] * invs);
                }
            }
        }
    }
}

// ---- K6: O = ctxm(fp32) @ Wo^T -> fp32 d_out ----
__global__ __launch_bounds__(256) void k_out(const float* __restrict__ ctxm,
                                             const u16* __restrict__ Wo, float* __restrict__ out) {
    __shared__ __align__(16) u16 As[128 * LST], Bs[128 * LST];
    floatx4 acc[4][4];
#pragma unroll
    for (int i = 0; i < 4; ++i)
#pragma unroll
        for (int j = 0; j < 4; ++j) acc[i][j] = (floatx4)(0.f);
    int b = blockIdx.z;
    const float* A = ctxm + (size_t)b * Ss * Cc;
    int mbase = blockIdx.y * 128, nbase = blockIdx.x * 128;
    int tid = threadIdx.x, lane = tid & 63, wave = tid >> 6, wm = wave >> 1, wn = wave & 1;
    int row0 = tid >> 2, row1 = 64 + row0;
    int cole = (tid & 3) << 3;
    int ga0 = mbase + row0; ga0 = ga0 <= Ss - 1 ? ga0 : Ss - 1;
    int ga1 = mbase + row1; ga1 = ga1 <= Ss - 1 ? ga1 : Ss - 1;
    const float* pa0 = A + (size_t)ga0 * Cc + cole;
    const float* pa1 = A + (size_t)ga1 * Cc + cole;
    const u16* pb0 = Wo + (size_t)(nbase + row0 <= Cc - 1 ? nbase + row0 : Cc - 1) * Cc + cole;
    const u16* pb1 = Wo + (size_t)(nbase + row1 <= Cc - 1 ? nbase + row1 : Cc - 1) * Cc + cole;
    float4 a00 = *(const float4*)(pa0), a01 = *(const float4*)(pa0 + 4);
    float4 a10 = *(const float4*)(pa1), a11 = *(const float4*)(pa1 + 4);
    shortx8 vb0 = *(const shortx8*)(pb0);
    shortx8 vb1 = *(const shortx8*)(pb1);
    for (int k0 = 0; k0 < Cc; k0 += 32) {
        shortx8 o0, o1;
        o0[0] = (short)f2bf(a00.x); o0[1] = (short)f2bf(a00.y); o0[2] = (short)f2bf(a00.z); o0[3] = (short)f2bf(a00.w);
        o0[4] = (short)f2bf(a01.x); o0[5] = (short)f2bf(a01.y); o0[6] = (short)f2bf(a01.z); o0[7] = (short)f2bf(a01.w);
        o1[0] = (short)f2bf(a10.x); o1[1] = (short)f2bf(a10.y); o1[2] = (short)f2bf(a10.z); o1[3] = (short)f2bf(a10.w);
        o1[4] = (short)f2bf(a11.x); o1[5] = (short)f2bf(a11.y); o1[6] = (short)f2bf(a11.z); o1[7] = (short)f2bf(a11.w);
        __syncthreads();
        *(shortx8*)(As + row0 * LST + cole) = o0;
        *(shortx8*)(As + row1 * LST + cole) = o1;
        *(shortx8*)(Bs + row0 * LST + cole) = vb0;
        *(shortx8*)(Bs + row1 * LST + cole) = vb1;
        int k1 = k0 + 32;
        if (k1 < Cc) {
            a00 = *(const float4*)(pa0 + k1); a01 = *(const float4*)(pa0 + k1 + 4);
            a10 = *(const float4*)(pa1 + k1); a11 = *(const float4*)(pa1 + k1 + 4);
            vb0 = *(const shortx8*)(pb0 + k1);
            vb1 = *(const shortx8*)(pb1 + k1);
        }
        __syncthreads();
        mfma_step(As, Bs, lane, wm, wn, acc);
    }
    int rq = (lane >> 4) << 2, cn = lane & 15;
    float* o = out + (size_t)b * Ss * Cc;
#pragma unroll
    for (int i = 0; i < 4; ++i) {
        int mb = mbase + wm * 64 + i * 16 + rq;
#pragma unroll
        for (int j = 0; j < 4; ++j) {
            int n = nbase + wn * 64 + j * 16 + cn;
#pragma unroll
            for (int r = 0; r < 4; ++r) {
                int m = mb + r;
                if (m < Ss) o[(size_t)m * Cc + n] = acc[i][j][r];
            }
        }
    }
}

extern "C" void kernel_launch(void* const* d_in, const int* in_sizes, int n_in,
                              void* d_out, int out_size, void* d_ws, size_t ws_size,
                              hipStream_t stream) {
    const float* emb = (const float*)d_in[0];
    float* out = (float*)d_out;

    char* ws = (char*)d_ws;
    size_t off = 0;
    auto alloc = [&](size_t bytes) -> void* {
        void* p = ws + off;
        off = (off + bytes + 255) & ~(size_t)255;
        return p;
    };
    float* stats = (float*)alloc(16 * 4 * sizeof(float));
    u16* Wall = (u16*)alloc((size_t)(3 * Hh + 1) * Cc * Cc * 2);
    u16* x    = (u16*)alloc((size_t)Bb * Ss * Cc * 2);
    u16* Q    = (u16*)alloc((size_t)Bb * Hh * Ss * Cc * 2);
    u16* Kb   = (u16*)alloc((size_t)Bb * Hh * Ss * Cc * 2);
    u16* Vt   = (u16*)alloc((size_t)Bb * Hh * Ss * Cc * 2);
    float* ctxm = (float*)alloc((size_t)Bb * Ss * Cc * 4);
    u16* Woc  = Wall + (size_t)3 * Hh * Cc * Cc;

    hipMemsetAsync(stats, 0, 16 * 4 * sizeof(float), stream);
    hipMemsetAsync(ctxm, 0, (size_t)Bb * Ss * Cc * 4, stream);

    k_convall<<<dim3(3328), dim3(256), 0, stream>>>((const float*)d_in[1], (const float*)d_in[2],
                                                    (const float*)d_in[3], (const float*)d_in[4], Wall);
    k_transpose<<<dim3(7, 8, 32), dim3(32, 8), 0, stream>>>(emb, x);
    k_qkv<<<dim3(2, 13, 48), dim3(256), 0, stream>>>(x, Wall, Q, Kb, Vt);
    k_stats<<<dim3(2704), dim3(256), 0, stream>>>(Q, Kb, stats);
    k_fused<<<dim3(400), dim3(256), 75520, stream>>>(Q, Kb, Vt, stats, ctxm);
    k_out<<<dim3(2, 13, 4), dim3(256), 0, stream>>>(ctxm, Woc, out);
}

// Round 14
// 213.740 us; speedup vs baseline: 1.0726x; 1.0726x over previous
//
#include <hip/hip_runtime.h>
#include <stdint.h>

typedef unsigned short u16;

#define Bb 4
#define Hh 4
#define Tt 8
#define Cc 256
#define NP 196
#define Ss 1568                 // Tt*NP
#define SCALE_S 0.0252538136f   // 1/sqrt(1568)
#define LST 32                  // LDS row stride for gemm_bt_core tiles
#define KC 64                   // k_fused KV chunk
#define NCH 25                  // ceil(1568/64)
#define LPP 72                  // P tile row stride (64+8)

typedef __attribute__((ext_vector_type(4))) float floatx4;
typedef __attribute__((ext_vector_type(8))) short shortx8;

__device__ __forceinline__ float bf2f(u16 u) {
    union { unsigned u; float f; } v; v.u = ((unsigned)u) << 16; return v.f;
}
__device__ __forceinline__ u16 f2bf(float f) {
    union { float f; unsigned u; } v; v.f = f;
    unsigned r = v.u + 0x7FFFu + ((v.u >> 16) & 1u);
    return (u16)(r >> 16);
}

typedef const __attribute__((address_space(1))) void* gas1_t;
typedef __attribute__((address_space(3))) void* las3_t;
__device__ __forceinline__ void gld16(const void* g, void* l) {
    __builtin_amdgcn_global_load_lds((gas1_t)g, (las3_t)l, 16, 0, 0);
}

// ---- K0: all weights fp32 -> one bf16 buffer [Wq|Wk|Wv|Wo] ----
__global__ __launch_bounds__(256) void k_convall(const float* __restrict__ Wq,
                                                 const float* __restrict__ Wk,
                                                 const float* __restrict__ Wv,
                                                 const float* __restrict__ Wo,
                                                 u16* __restrict__ dst) {
    const int NW = Hh * Cc * Cc;     // 262144
    int i = blockIdx.x * 256 + threadIdx.x;
    float v;
    if (i < NW) v = Wq[i];
    else if (i < 2 * NW) v = Wk[i - NW];
    else if (i < 3 * NW) v = Wv[i - 2 * NW];
    else if (i < 3 * NW + Cc * Cc) v = Wo[i - 3 * NW];
    else return;
    dst[i] = f2bf(v);
}

// One BK=32 step: 4x4 grid of 16x16x32 bf16 MFMAs per wave (wave covers 64x64).
__device__ __forceinline__ void mfma_step(const u16* As, const u16* Bs, int lane,
                                          int wm, int wn, floatx4 acc[4][4]) {
    const int r15 = lane & 15;
    const int kq  = (lane >> 4) << 3;
    shortx8 a[4], b[4];
#pragma unroll
    for (int i = 0; i < 4; ++i)
        a[i] = *(const shortx8*)(As + (wm * 64 + i * 16 + r15) * LST + kq);
#pragma unroll
    for (int j = 0; j < 4; ++j)
        b[j] = *(const shortx8*)(Bs + (wn * 64 + j * 16 + r15) * LST + kq);
#pragma unroll
    for (int i = 0; i < 4; ++i)
#pragma unroll
        for (int j = 0; j < 4; ++j)
            acc[i][j] = __builtin_amdgcn_mfma_f32_16x16x32_bf16(a[i], b[j], acc[i][j], 0, 0, 0);
}

// C[m,n] = sum_k A[m,k]*B[n,k], 128x128 tile, depth-2 prefetch. KD multiple of 32.
__device__ __forceinline__ void gemm_bt_core(const u16* A, const u16* Bm, int lda, int ldb,
                                             int mbase, int mlast, int nbase, int nlast,
                                             int KD, u16* As, u16* Bs, floatx4 acc[4][4]) {
    int tid = threadIdx.x;
    int lane = tid & 63, wave = tid >> 6, wm = wave >> 1, wn = wave & 1;
    int row0 = tid >> 2, row1 = 64 + row0;
    int cole = (tid & 3) << 3;                 // 0,8,16,24
    int ga0 = mbase + row0; ga0 = ga0 <= mlast ? ga0 : mlast;
    int ga1 = mbase + row1; ga1 = ga1 <= mlast ? ga1 : mlast;
    int gb0 = nbase + row0; gb0 = gb0 <= nlast ? gb0 : nlast;
    int gb1 = nbase + row1; gb1 = gb1 <= nlast ? gb1 : nlast;
    const u16* pa0 = A  + (size_t)ga0 * lda + cole;
    const u16* pa1 = A  + (size_t)ga1 * lda + cole;
    const u16* pb0 = Bm + (size_t)gb0 * ldb + cole;
    const u16* pb1 = Bm + (size_t)gb1 * ldb + cole;
    shortx8 xa0 = *(const shortx8*)(pa0),      xa1 = *(const shortx8*)(pa1);
    shortx8 xb0 = *(const shortx8*)(pb0),      xb1 = *(const shortx8*)(pb1);
    shortx8 ya0 = *(const shortx8*)(pa0 + 32), ya1 = *(const shortx8*)(pa1 + 32);
    shortx8 yb0 = *(const shortx8*)(pb0 + 32), yb1 = *(const shortx8*)(pb1 + 32);
    for (int k0 = 0; k0 < KD; k0 += 64) {
        __syncthreads();
        *(shortx8*)(As + row0 * LST + cole) = xa0;
        *(shortx8*)(As + row1 * LST + cole) = xa1;
        *(shortx8*)(Bs + row0 * LST + cole) = xb0;
        *(shortx8*)(Bs + row1 * LST + cole) = xb1;
        int kp = k0 + 64;
        if (kp < KD) {
            xa0 = *(const shortx8*)(pa0 + kp); xa1 = *(const shortx8*)(pa1 + kp);
            xb0 = *(const shortx8*)(pb0 + kp); xb1 = *(const shortx8*)(pb1 + kp);
        }
        __syncthreads();
        mfma_step(As, Bs, lane, wm, wn, acc);
        if (k0 + 32 < KD) {
            __syncthreads();
            *(shortx8*)(As + row0 * LST + cole) = ya0;
            *(shortx8*)(As + row1 * LST + cole) = ya1;
            *(shortx8*)(Bs + row0 * LST + cole) = yb0;
            *(shortx8*)(Bs + row1 * LST + cole) = yb1;
            int kq2 = k0 + 96;
            if (kq2 < KD) {
                ya0 = *(const shortx8*)(pa0 + kq2); ya1 = *(const shortx8*)(pa1 + kq2);
                yb0 = *(const shortx8*)(pb0 + kq2); yb1 = *(const shortx8*)(pb1 + kq2);
            }
            __syncthreads();
            mfma_step(As, Bs, lane, wm, wn, acc);
        }
    }
}

// ---- K1: emb fp32 [B,T,C,N] -> x bf16 [B,S,C] ----
__global__ void k_transpose(const float* __restrict__ emb, u16* __restrict__ x) {
    __shared__ u16 tile[32][33];
    int bt = blockIdx.z;
    int c0 = blockIdx.y * 32, n0 = blockIdx.x * 32;
    const float* src = emb + (size_t)bt * Cc * NP;
#pragma unroll
    for (int rr = 0; rr < 32; rr += 8) {
        int c = c0 + threadIdx.y + rr;
        int n = n0 + threadIdx.x;
        u16 v = 0;
        if (n < NP) v = f2bf(src[(size_t)c * NP + n]);
        tile[threadIdx.y + rr][threadIdx.x] = v;
    }
    __syncthreads();
    int b = bt / Tt, t = bt % Tt;
    u16* dst = x + ((size_t)b * Ss + (size_t)t * NP) * Cc;
#pragma unroll
    for (int rr = 0; rr < 32; rr += 8) {
        int n = n0 + threadIdx.y + rr;
        int c = c0 + threadIdx.x;
        if (n < NP) dst[(size_t)n * Cc + c] = tile[threadIdx.x][threadIdx.y + rr];
    }
}

// ---- K2: QKV projections (r7 form). Q,K row-major + Qt,Kt,Vt transposed [C,S].
// Column sums of Q,K (raw, for stats mean) fused into the epilogue. ----
__global__ __launch_bounds__(256) void k_qkv(const u16* __restrict__ x,
                                             const u16* __restrict__ Wall,
                                             u16* __restrict__ Q, u16* __restrict__ Kb,
                                             u16* __restrict__ Vt, u16* __restrict__ Qt,
                                             u16* __restrict__ Kt, float* __restrict__ cs) {
    __shared__ __align__(16) u16 As[128 * LST], Bs[128 * LST];
    floatx4 acc[4][4];
#pragma unroll
    for (int i = 0; i < 4; ++i)
#pragma unroll
        for (int j = 0; j < 4; ++j) acc[i][j] = (floatx4)(0.f);
    int z = blockIdx.z;
    int qkv = z >> 4, bh = z & 15, b = bh >> 2, h = bh & 3;
    const u16* A = x + (size_t)b * Ss * Cc;
    const u16* W = Wall + (size_t)qkv * Hh * Cc * Cc + (size_t)h * Cc * Cc;
    int mbase = blockIdx.y * 128, nbase = blockIdx.x * 128;
    gemm_bt_core(A, W, Cc, Cc, mbase, Ss - 1, nbase, Cc - 1, Cc, As, Bs, acc);

    int tid = threadIdx.x, lane = tid & 63, wave = tid >> 6, wm = wave >> 1, wn = wave & 1;
    int rq = (lane >> 4) << 2, cn = lane & 15;
    if (qkv < 2) {
        u16* outr = (qkv == 0 ? Q : Kb) + (size_t)bh * Ss * Cc;
        u16* outt = (qkv == 0 ? Qt : Kt) + (size_t)bh * Cc * Ss;
#pragma unroll
        for (int i = 0; i < 4; ++i) {
            int m0 = mbase + wm * 64 + i * 16 + rq;
#pragma unroll
            for (int j = 0; j < 4; ++j) {
                int n = nbase + wn * 64 + j * 16 + cn;
                ushort4 v;
                v.x = f2bf(acc[i][j][0]); v.y = f2bf(acc[i][j][1]);
                v.z = f2bf(acc[i][j][2]); v.w = f2bf(acc[i][j][3]);
#pragma unroll
                for (int r = 0; r < 4; ++r) {
                    int m = m0 + r;
                    if (m < Ss) outr[(size_t)m * Cc + n] = f2bf(acc[i][j][r]);
                }
                if (m0 < Ss) *(ushort4*)(outt + (size_t)n * Ss + m0) = v;
            }
        }
        // fused column sums: cs[qkv*16+bh][n] += sum_m acc  (mask tail rows)
#pragma unroll
        for (int j = 0; j < 4; ++j) {
            float s = 0.f;
#pragma unroll
            for (int i = 0; i < 4; ++i) {
                int m0 = mbase + wm * 64 + i * 16 + rq;
#pragma unroll
                for (int r = 0; r < 4; ++r)
                    if (m0 + r < Ss) s += acc[i][j][r];
            }
            s += __shfl_xor(s, 16); s += __shfl_xor(s, 32);
            if ((lane >> 4) == 0) {
                int n = nbase + wn * 64 + j * 16 + cn;
                atomicAdd(&cs[(size_t)(qkv * 16 + bh) * Cc + n], s);
            }
        }
    } else {
        u16* out = Vt + (size_t)bh * Cc * Ss;
#pragma unroll
        for (int i = 0; i < 4; ++i) {
            int m0 = mbase + wm * 64 + i * 16 + rq;
            if (m0 < Ss) {
#pragma unroll
                for (int j = 0; j < 4; ++j) {
                    int n = nbase + wn * 64 + j * 16 + cn;
                    ushort4 v;
                    v.x = f2bf(acc[i][j][0]); v.y = f2bf(acc[i][j][1]);
                    v.z = f2bf(acc[i][j][2]); v.w = f2bf(acc[i][j][3]);
                    *(ushort4*)(out + (size_t)n * Ss + m0) = v;
                }
            }
        }
    }
}

// ---- K3a: split-K Gram partials. z = qk*64 + bh*4 + ks; each block computes one
// 128x128 tile of (Qt or Kt) Gram over K-slice [ks*384, +384/416) -> Gp[z].
// 512 blocks (2/CU): fixes r8's 64-block underparallelization of the same math. ----
__global__ __launch_bounds__(256) void k_gram(const u16* __restrict__ Qt,
                                              const u16* __restrict__ Kt,
                                              float* __restrict__ Gp) {
    __shared__ __align__(16) u16 As[128 * LST], Bs[128 * LST];
    floatx4 acc[4][4];
#pragma unroll
    for (int i = 0; i < 4; ++i)
#pragma unroll
        for (int j = 0; j < 4; ++j) acc[i][j] = (floatx4)(0.f);
    int z = blockIdx.z;
    int qk = z >> 6, rem = z & 63, bh = rem >> 2, ks = rem & 3;
    int kstart = ks * 384;
    int klen = (ks == 3) ? 416 : 384;      // 3*384+416 = 1568; both multiples of 32
    const u16* T = (qk ? Kt : Qt) + (size_t)bh * Cc * Ss + kstart;
    int mbase = blockIdx.y * 128, nbase = blockIdx.x * 128;
    gemm_bt_core(T, T, Ss, Ss, mbase, Cc - 1, nbase, Cc - 1, klen, As, Bs, acc);

    int tid = threadIdx.x, lane = tid & 63, wave = tid >> 6, wm = wave >> 1, wn = wave & 1;
    int rq = (lane >> 4) << 2, cn = lane & 15;
    float* o = Gp + (size_t)z * (Cc * Cc);
#pragma unroll
    for (int i = 0; i < 4; ++i) {
        int mb = mbase + wm * 64 + i * 16 + rq;
#pragma unroll
        for (int j = 0; j < 4; ++j) {
            int n = nbase + wn * 64 + j * 16 + cn;
#pragma unroll
            for (int r = 0; r < 4; ++r)
                o[(size_t)(mb + r) * Cc + n] = acc[i][j][r];
        }
    }
}

// ---- K3b: stats[bh*4+0] = SCALE_S * sumQ.sumK ; stats[bh*4+1] = SCALE_S^2 * <Gq,Gk>.
// Grid (8,16): 128 blocks stream the 33.5 MB of Gram partials. ----
__global__ __launch_bounds__(256) void k_dot(const float* __restrict__ Gp,
                                             const float* __restrict__ cs,
                                             float* __restrict__ stats) {
    __shared__ float red[4];
    int bh = blockIdx.y;
    int tid = threadIdx.x, lane = tid & 63, wave = tid >> 6;
    const size_t CC2 = (size_t)Cc * Cc;    // 65536
    size_t bq = (size_t)(bh << 2) * CC2;          // qk=0 slices
    size_t bk = (size_t)(64 + (bh << 2)) * CC2;   // qk=1 slices
    float s2 = 0.f;
    int e0 = blockIdx.x * 8192;
#pragma unroll 4
    for (int i = 0; i < 32; ++i) {
        int e = e0 + i * 256 + tid;
        float gq = Gp[bq + e] + Gp[bq + CC2 + e] + Gp[bq + 2 * CC2 + e] + Gp[bq + 3 * CC2 + e];
        float gk = Gp[bk + e] + Gp[bk + CC2 + e] + Gp[bk + 2 * CC2 + e] + Gp[bk + 3 * CC2 + e];
        s2 += gq * gk;
    }
#pragma unroll
    for (int mk = 1; mk <= 32; mk <<= 1) s2 += __shfl_xor(s2, mk);
    __syncthreads();
    if (lane == 0) red[wave] = s2;
    __syncthreads();
    if (tid == 0)
        atomicAdd(&stats[bh * 4 + 1], (red[0] + red[1] + red[2] + red[3]) * (SCALE_S * SCALE_S));
    if (blockIdx.x == 0) {
        float s1 = cs[(size_t)bh * Cc + tid] * cs[(size_t)(16 + bh) * Cc + tid];
#pragma unroll
        for (int mk = 1; mk <= 32; mk <<= 1) s1 += __shfl_xor(s1, mk);
        __syncthreads();
        if (lane == 0) red[wave] = s1;
        __syncthreads();
        if (tid == 0)
            atomicAdd(&stats[bh * 4 + 0], (red[0] + red[1] + red[2] + red[3]) * SCALE_S);
    }
}

// ---- K4: fused QK^T + norm + exp + PV + head-mean (r12 exact: best measured).
// M=64, 4 waves, KC=64, 400 blocks, LDS 75.5 KB. ----
__global__ __launch_bounds__(256, 2) void k_fused(const u16* __restrict__ Q,
                                                  const u16* __restrict__ Kb,
                                                  const u16* __restrict__ Vt,
                                                  const float* __restrict__ stats,
                                                  float* __restrict__ ctxm) {
    extern __shared__ u16 smem[];
    u16* Kls = smem;                             // 2 x [64][256] linear+swz = 65536 B
    u16* Ps  = smem + 32768;                     // [64][LPP] = 9216 B
    float* rsp = (float*)((char*)smem + 74752);  // [2][64]
    float* rs2 = rsp + 128;                      // [64]

    int L = blockIdx.x;                      // 400 = 8 xcd * 2 bh * 25 m-tiles
    int xcd = L & 7, idx = L >> 3;
    int bh = xcd + 8 * (idx / 25);
    int mt = idx % 25;
    int mbase = mt * 64;

    float inv  = 1.f / ((float)Ss * (float)Ss);
    float mean = stats[bh * 4] * inv;
    float var  = fmaxf(stats[bh * 4 + 1] * inv - mean * mean, 0.f);
    float istd = rsqrtf(var + 1e-5f);
    float aa   = istd * 1.44269504f;
    float aas  = aa * SCALE_S;
    float bb   = -mean * aa;

    const u16* Qp = Q  + (size_t)bh * Ss * Cc;
    const u16* Kp = Kb + (size_t)bh * Ss * Cc;
    const u16* Vp = Vt + (size_t)bh * Cc * Ss;

    int tid = threadIdx.x, lane = tid & 63, wv = tid >> 6;
    const int r15 = lane & 15;
    const int g   = lane >> 4;
    const int kq  = g << 3;                  // elem offset of k-slice
    const int prow = g << 2;
    const int wqm = wv >> 1, wqn = wv & 1;   // QK^T wave grid: 2m x 2n
    const int swz = (r15 & 7) << 4;          // read-side XOR (Kls)

    // ---- Q fragments -> registers (once). QK^T wave owns rows [wqm*32, +32). ----
    shortx8 Qa[8][2];
#pragma unroll
    for (int kk = 0; kk < 8; ++kk)
#pragma unroll
        for (int i = 0; i < 2; ++i) {
            int row = mbase + wqm * 32 + i * 16 + r15;
            row = row < Ss ? row : Ss - 1;
            Qa[kk][i] = *(const shortx8*)(Qp + (size_t)row * Cc + kk * 32 + kq);
        }

    // ---- prologue: DMA K chunk 0 (pre-swizzled source, linear dest) ----
#pragma unroll
    for (int pass = 0; pass < 8; ++pass) {
        int rb = pass * 4 + wv;              // 2-row unit (0..31)
        int r2 = rb * 2 + (lane >> 5);
        int colb = (lane & 31) << 4;
        int scol = colb ^ ((r2 & 7) << 4);
        gld16((const char*)Kp + (size_t)r2 * 512 + scol, Kls + rb * 512);
    }
    __syncthreads();

    floatx4 acc[4][4];
#pragma unroll
    for (int i = 0; i < 4; ++i)
#pragma unroll
        for (int j = 0; j < 4; ++j) acc[i][j] = (floatx4)(0.f);
    float rsum[2][4];
    rsum[0][0] = rsum[0][1] = rsum[0][2] = rsum[0][3] = 0.f;
    rsum[1][0] = rsum[1][1] = rsum[1][2] = rsum[1][3] = 0.f;

    int cur = 0;
    for (int c = 0; c < NCH; ++c) {
        int kc = c * KC;
        const u16* Kcur = Kls + cur * 16384;
        // issue DMA of next K chunk (flies across QK^T, drained at first barrier)
        if (c + 1 < NCH) {
            int kc1 = kc + KC;
            u16* Knxt = Kls + (cur ^ 1) * 16384;
#pragma unroll
            for (int pass = 0; pass < 8; ++pass) {
                int rb = pass * 4 + wv;
                int r2 = rb * 2 + (lane >> 5);
                int colb = (lane & 31) << 4;
                int scol = colb ^ ((r2 & 7) << 4);
                int grow = kc1 + r2; grow = grow < Ss ? grow : 0;
                gld16((const char*)Kp + (size_t)grow * 512 + scol, Knxt + rb * 512);
            }
        }
        // prefetch V frags (PV wave owns ctx cols [wv*64,+64)); 8 loads
        shortx8 vf[2][4];
#pragma unroll
        for (int kk2 = 0; kk2 < 2; ++kk2)
#pragma unroll
            for (int nj = 0; nj < 4; ++nj) {
                int vr = wv * 64 + nj * 16 + r15;
                int vc = kc + kk2 * 32 + kq;
                vc = (vc + 8 <= Ss) ? vc : 0;
                vf[kk2][nj] = *(const shortx8*)(Vp + (size_t)vr * Ss + vc);
            }
        // ---- QK^T: wave tile 32 rows x 32 kv cols ----
        floatx4 accs[2][2];
        accs[0][0] = (floatx4)(0.f); accs[0][1] = (floatx4)(0.f);
        accs[1][0] = (floatx4)(0.f); accs[1][1] = (floatx4)(0.f);
        const int cb = g << 4;
#pragma unroll
        for (int kk = 0; kk < 8; ++kk) {
            int cbx = (kk * 64 + cb) ^ swz;
            shortx8 b0 = *(const shortx8*)((const char*)Kcur + (wqn * 32 + r15) * 512 + cbx);
            shortx8 b1 = *(const shortx8*)((const char*)Kcur + (wqn * 32 + 16 + r15) * 512 + cbx);
            accs[0][0] = __builtin_amdgcn_mfma_f32_16x16x32_bf16(Qa[kk][0], b0, accs[0][0], 0, 0, 0);
            accs[1][0] = __builtin_amdgcn_mfma_f32_16x16x32_bf16(Qa[kk][1], b0, accs[1][0], 0, 0, 0);
            accs[0][1] = __builtin_amdgcn_mfma_f32_16x16x32_bf16(Qa[kk][0], b1, accs[0][1], 0, 0, 0);
            accs[1][1] = __builtin_amdgcn_mfma_f32_16x16x32_bf16(Qa[kk][1], b1, accs[1][1], 0, 0, 0);
        }
        // ---- exp on fp32 acc; mask invalid kv cols; accumulate row sums ----
#pragma unroll
        for (int j = 0; j < 2; ++j) {
            bool valid = (kc + wqn * 32 + j * 16 + r15) < Ss;
#pragma unroll
            for (int i = 0; i < 2; ++i)
#pragma unroll
                for (int r = 0; r < 4; ++r) {
                    float ex = valid ? exp2f(accs[i][j][r] * aas + bb) : 0.f;
                    accs[i][j][r] = ex;
                    rsum[i][r] += ex;
                }
        }
        __syncthreads();   // prev PV's P-readers done (also drains DMA/V loads)
        // ---- write P (D-layout -> row-major [m][kv]) ----
#pragma unroll
        for (int i = 0; i < 2; ++i)
#pragma unroll
            for (int j = 0; j < 2; ++j)
#pragma unroll
                for (int r = 0; r < 4; ++r)
                    Ps[(wqm * 32 + i * 16 + prow + r) * LPP + wqn * 32 + j * 16 + r15] =
                        f2bf(accs[i][j][r]);
        __syncthreads();
        // ---- PV: wave owns all 64 rows x ctx cols [wv*64,+64) ----
#pragma unroll
        for (int kk2 = 0; kk2 < 2; ++kk2) {
            shortx8 pa_[4];
#pragma unroll
            for (int i2 = 0; i2 < 4; ++i2)
                pa_[i2] = *(const shortx8*)(Ps + (i2 * 16 + r15) * LPP + kk2 * 32 + kq);
#pragma unroll
            for (int i2 = 0; i2 < 4; ++i2)
#pragma unroll
                for (int nj = 0; nj < 4; ++nj)
                    acc[i2][nj] = __builtin_amdgcn_mfma_f32_16x16x32_bf16(
                        pa_[i2], vf[kk2][nj], acc[i2][nj], 0, 0, 0);
        }
        cur ^= 1;
    }

    // ---- row-sum: reduce over 16 col-lanes, combine the two wqn halves ----
#pragma unroll
    for (int i = 0; i < 2; ++i)
#pragma unroll
        for (int r = 0; r < 4; ++r) {
            float v = rsum[i][r];
            v += __shfl_xor(v, 1); v += __shfl_xor(v, 2);
            v += __shfl_xor(v, 4); v += __shfl_xor(v, 8);
            if (r15 == 0) rsp[wqn * 64 + wqm * 32 + i * 16 + prow + r] = v;
        }
    __syncthreads();
    if (tid < 64) rs2[tid] = rsp[tid] + rsp[64 + tid];
    __syncthreads();

    // ---- fused head-mean: ctxm[b,m,n] += 0.25 * acc / rowsum[m] ----
    int b = bh >> 2;
    float* outp = ctxm + (size_t)b * Ss * Cc;
#pragma unroll
    for (int i2 = 0; i2 < 4; ++i2) {
#pragma unroll
        for (int r = 0; r < 4; ++r) {
            int ml = i2 * 16 + prow + r;
            int m = mbase + ml;
            if (m < Ss) {
                float invs = 0.25f / rs2[ml];
#pragma unroll
                for (int nj = 0; nj < 4; ++nj) {
                    int n = wv * 64 + nj * 16 + r15;
                    atomicAdd(&outp[(size_t)m * Cc + n], acc[i2][nj][r] * invs);
                }
            }
        }
    }
}

// ---- K6: O = ctxm(fp32) @ Wo^T -> fp32 d_out ----
__global__ __launch_bounds__(256) void k_out(const float* __restrict__ ctxm,
                                             const u16* __restrict__ Wo, float* __restrict__ out) {
    __shared__ __align__(16) u16 As[128 * LST], Bs[128 * LST];
    floatx4 acc[4][4];
#pragma unroll
    for (int i = 0; i < 4; ++i)
#pragma unroll
        for (int j = 0; j < 4; ++j) acc[i][j] = (floatx4)(0.f);
    int b = blockIdx.z;
    const float* A = ctxm + (size_t)b * Ss * Cc;
    int mbase = blockIdx.y * 128, nbase = blockIdx.x * 128;
    int tid = threadIdx.x, lane = tid & 63, wave = tid >> 6, wm = wave >> 1, wn = wave & 1;
    int row0 = tid >> 2, row1 = 64 + row0;
    int cole = (tid & 3) << 3;
    int ga0 = mbase + row0; ga0 = ga0 <= Ss - 1 ? ga0 : Ss - 1;
    int ga1 = mbase + row1; ga1 = ga1 <= Ss - 1 ? ga1 : Ss - 1;
    const float* pa0 = A + (size_t)ga0 * Cc + cole;
    const float* pa1 = A + (size_t)ga1 * Cc + cole;
    const u16* pb0 = Wo + (size_t)(nbase + row0 <= Cc - 1 ? nbase + row0 : Cc - 1) * Cc + cole;
    const u16* pb1 = Wo + (size_t)(nbase + row1 <= Cc - 1 ? nbase + row1 : Cc - 1) * Cc + cole;
    float4 a00 = *(const float4*)(pa0), a01 = *(const float4*)(pa0 + 4);
    float4 a10 = *(const float4*)(pa1), a11 = *(const float4*)(pa1 + 4);
    shortx8 vb0 = *(const shortx8*)(pb0);
    shortx8 vb1 = *(const shortx8*)(pb1);
    for (int k0 = 0; k0 < Cc; k0 += 32) {
        shortx8 o0, o1;
        o0[0] = (short)f2bf(a00.x); o0[1] = (short)f2bf(a00.y); o0[2] = (short)f2bf(a00.z); o0[3] = (short)f2bf(a00.w);
        o0[4] = (short)f2bf(a01.x); o0[5] = (short)f2bf(a01.y); o0[6] = (short)f2bf(a01.z); o0[7] = (short)f2bf(a01.w);
        o1[0] = (short)f2bf(a10.x); o1[1] = (short)f2bf(a10.y); o1[2] = (short)f2bf(a10.z); o1[3] = (short)f2bf(a10.w);
        o1[4] = (short)f2bf(a11.x); o1[5] = (short)f2bf(a11.y); o1[6] = (short)f2bf(a11.z); o1[7] = (short)f2bf(a11.w);
        __syncthreads();
        *(shortx8*)(As + row0 * LST + cole) = o0;
        *(shortx8*)(As + row1 * LST + cole) = o1;
        *(shortx8*)(Bs + row0 * LST + cole) = vb0;
        *(shortx8*)(Bs + row1 * LST + cole) = vb1;
        int k1 = k0 + 32;
        if (k1 < Cc) {
            a00 = *(const float4*)(pa0 + k1); a01 = *(const float4*)(pa0 + k1 + 4);
            a10 = *(const float4*)(pa1 + k1); a11 = *(const float4*)(pa1 + k1 + 4);
            vb0 = *(const shortx8*)(pb0 + k1);
            vb1 = *(const shortx8*)(pb1 + k1);
        }
        __syncthreads();
        mfma_step(As, Bs, lane, wm, wn, acc);
    }
    int rq = (lane >> 4) << 2, cn = lane & 15;
    float* o = out + (size_t)b * Ss * Cc;
#pragma unroll
    for (int i = 0; i < 4; ++i) {
        int mb = mbase + wm * 64 + i * 16 + rq;
#pragma unroll
        for (int j = 0; j < 4; ++j) {
            int n = nbase + wn * 64 + j * 16 + cn;
#pragma unroll
            for (int r = 0; r < 4; ++r) {
                int m = mb + r;
                if (m < Ss) o[(size_t)m * Cc + n] = acc[i][j][r];
            }
        }
    }
}

extern "C" void kernel_launch(void* const* d_in, const int* in_sizes, int n_in,
                              void* d_out, int out_size, void* d_ws, size_t ws_size,
                              hipStream_t stream) {
    const float* emb = (const float*)d_in[0];
    float* out = (float*)d_out;

    char* ws = (char*)d_ws;
    size_t off = 0;
    auto alloc = [&](size_t bytes) -> void* {
        void* p = ws + off;
        off = (off + bytes + 255) & ~(size_t)255;
        return p;
    };
    float* stats = (float*)alloc(16 * 4 * sizeof(float));
    u16* Wall = (u16*)alloc((size_t)(3 * Hh + 1) * Cc * Cc * 2);
    u16* x    = (u16*)alloc((size_t)Bb * Ss * Cc * 2);
    u16* Q    = (u16*)alloc((size_t)Bb * Hh * Ss * Cc * 2);
    u16* Kb   = (u16*)alloc((size_t)Bb * Hh * Ss * Cc * 2);
    u16* Vt   = (u16*)alloc((size_t)Bb * Hh * Ss * Cc * 2);
    u16* Qt   = (u16*)alloc((size_t)Bb * Hh * Ss * Cc * 2);
    u16* Kt   = (u16*)alloc((size_t)Bb * Hh * Ss * Cc * 2);
    float* ctxm = (float*)alloc((size_t)Bb * Ss * Cc * 4);
    float* Gp   = (float*)alloc((size_t)128 * Cc * Cc * 4);      // 33.5 MiB gram partials
    float* cs   = (float*)alloc((size_t)32 * Cc * 4);            // colsums Q | K
    u16* Woc  = Wall + (size_t)3 * Hh * Cc * Cc;

    hipMemsetAsync(stats, 0, 16 * 4 * sizeof(float), stream);
    hipMemsetAsync(ctxm, 0, (size_t)Bb * Ss * Cc * 4, stream);
    hipMemsetAsync(cs, 0, (size_t)32 * Cc * 4, stream);

    k_convall<<<dim3(3328), dim3(256), 0, stream>>>((const float*)d_in[1], (const float*)d_in[2],
                                                    (const float*)d_in[3], (const float*)d_in[4], Wall);
    k_transpose<<<dim3(7, 8, 32), dim3(32, 8), 0, stream>>>(emb, x);
    k_qkv<<<dim3(2, 13, 48), dim3(256), 0, stream>>>(x, Wall, Q, Kb, Vt, Qt, Kt, cs);
    k_gram<<<dim3(2, 2, 128), dim3(256), 0, stream>>>(Qt, Kt, Gp);
    k_dot<<<dim3(8, 16), dim3(256), 0, stream>>>(Gp, cs, stats);
    k_fused<<<dim3(400), dim3(256), 75520, stream>>>(Q, Kb, Vt, stats, ctxm);
    k_out<<<dim3(2, 13, 4), dim3(256), 0, stream>>>(ctxm, Woc, out);
}